// Round 3
// baseline (726.040 us; speedup 1.0000x reference)
//
#include <hip/hip_runtime.h>
#include <hip/hip_bf16.h>
#include <stdint.h>

#define NUM_EXPERTS 32
#define HIDDEN 2048
#define INTER 2816
#define HALFI 1408
#define TOKENS 1024
#define TOPK 8
#define TA (TOKENS*TOPK)
#define CAP 512
#define BM 256
#define BK 32

typedef float f32x4 __attribute__((ext_vector_type(4)));
typedef __bf16 bf16x8 __attribute__((ext_vector_type(8)));

__device__ __forceinline__ uint32_t lrow(uint32_t row, uint32_t colbyte) {
  // 64-byte LDS rows (32 bf16); XOR row bits into 16B-slot bits -> ~4-way max conflict
  return row * 64u + (colbyte ^ ((row & 3u) << 4));
}
__device__ __forceinline__ uint32_t pk2(float a, float b) {
  union { __bf16 h[2]; uint32_t u; } c;
  c.h[0] = (__bf16)a; c.h[1] = (__bf16)b; return c.u;
}
__device__ __forceinline__ uint16_t bf16b(float a) {
  union { __bf16 h; uint16_t u; } c; c.h = (__bf16)a; return c.u;
}

// ---------------- routing ----------------
__global__ void route_count(const int* __restrict__ tkidx, int* __restrict__ offs) {
  __shared__ int cnt[NUM_EXPERTS];
  int tid = threadIdx.x;
  if (tid < NUM_EXPERTS) cnt[tid] = 0;
  __syncthreads();
  for (int i = tid; i < TA; i += 256) atomicAdd(&cnt[tkidx[i]], 1);
  __syncthreads();
  if (tid == 0) {
    int acc = 0;
    for (int e = 0; e < NUM_EXPERTS; ++e) { offs[e] = acc; acc += cnt[e]; }
    offs[NUM_EXPERTS] = acc;
  }
}

__global__ void route_build(const int* __restrict__ tkidx, const float* __restrict__ tkw,
                            const int* __restrict__ offs,
                            int* __restrict__ tok_of_row, float* __restrict__ w_of_row) {
  int e = blockIdx.x;
  int lane = threadIdx.x;
  int base = offs[e];
  int run = 0;
  for (int c0 = 0; c0 < TA; c0 += 64) {
    int i = c0 + lane;
    bool p = (tkidx[i] == e);
    unsigned long long m = __ballot(p);
    if (p) {
      int rank = run + __popcll(m & ((1ull << lane) - 1ull));
      if (rank < CAP) {
        tok_of_row[base + rank] = i >> 3;   // TOPK = 8
        w_of_row[base + rank]   = tkw[i];
      }
    }
    run += __popcll(m);
  }
}

// ---------------- GEMM1: h = X * W1^T, a = silu(gate)*up -> A_ws (bf16) ----------------
// BM=256 (4 waves x 64 rows), BN=64 (32 gate + 32 up), BK=32, 256 threads.
// LDS 40KB dbuf -> 3 blocks/CU (cross-block overlap hides per-block load drains).
__global__ __launch_bounds__(256, 3) void moe_gemm1(
    const float* __restrict__ hidden, const float* __restrict__ w1,
    const int* __restrict__ offs, const int* __restrict__ tok_of_row,
    uint16_t* __restrict__ A_ws)
{
  const int s = blockIdx.x;            // 2816 = 352*8
  const int xcd = s & 7, kk = s >> 3;  // kk: 0..351
  const int mt = kk & 1, pl = kk >> 1; // pl: 0..175
  const int pair = pl * 8 + xcd;       // 0..1407
  const int e = pair / 44, ns = pair % 44;

  const int off = offs[e];
  const int cnt = min(offs[e + 1] - off, CAP);
  if (mt * BM >= cnt) return;

  __shared__ __align__(16) char lds[40960];  // A dbuf 2x16KB @0, B dbuf 2x4KB @32768
  const int tid = threadIdx.x;
  const int rw = tid >> 3, ch = tid & 7;     // staging coords: 8 threads/row

  // A: rows j*32+rw (j<8), 4 f32 at col ch*4
  int rowoff[8];
  uint32_t wa[8];
#pragma unroll
  for (int j = 0; j < 8; ++j) {
    int row = j * 32 + rw;
    int grow = mt * BM + row;
    rowoff[j] = (grow < cnt) ? (tok_of_row[off + grow] * HIDDEN + ch * 4) : -1;
    wa[j] = lrow((uint32_t)row, (uint32_t)ch * 8);
  }
  // B: rows j*32+rw (j<2): rows 0..31 = gate cols ns*32+row; 32..63 = up cols HALFI+ns*32+(row-32)
  const float* bp[2];
  uint32_t wb[2];
#pragma unroll
  for (int j = 0; j < 2; ++j) {
    int row = j * 32 + rw;
    int col = (row < 32) ? (ns * 32 + row) : (HALFI + ns * 32 + (row - 32));
    bp[j] = w1 + ((size_t)e * INTER + col) * HIDDEN + ch * 4;
    wb[j] = lrow((uint32_t)row, (uint32_t)ch * 8);
  }

  f32x4 ra[8], rb[2];

  const int lane = tid & 63, wv = tid >> 6;
  const int wm = wv * 64;                    // wave owns 64 M rows
  const int fr = lane & 15, fq = lane >> 4;
  const bool active = (mt * BM + wm) < cnt;

  f32x4 acc[4][4];
#pragma unroll
  for (int i = 0; i < 4; ++i)
#pragma unroll
    for (int j = 0; j < 4; ++j) acc[i][j] = (f32x4)0.f;

  auto LOAD = [&](int k0) {
#pragma unroll
    for (int j = 0; j < 8; ++j)
      ra[j] = (rowoff[j] >= 0) ? *(const f32x4*)(hidden + rowoff[j] + k0) : (f32x4)0.f;
#pragma unroll
    for (int j = 0; j < 2; ++j)
      rb[j] = *(const f32x4*)(bp[j] + k0);
  };
  auto WRITE = [&](int buf) {
    char* pa = lds + buf * 16384;
    char* pb = lds + 32768 + buf * 4096;
#pragma unroll
    for (int j = 0; j < 8; ++j) {
      uint2 v; v.x = pk2(ra[j].x, ra[j].y); v.y = pk2(ra[j].z, ra[j].w);
      *(uint2*)(pa + wa[j]) = v;
    }
#pragma unroll
    for (int j = 0; j < 2; ++j) {
      uint2 v; v.x = pk2(rb[j].x, rb[j].y); v.y = pk2(rb[j].z, rb[j].w);
      *(uint2*)(pb + wb[j]) = v;
    }
  };

  const int NT = HIDDEN / BK;  // 64
  LOAD(0); WRITE(0);
  int cur = 0;
  for (int t = 0; t < NT; ++t) {
    __syncthreads();                       // buf[cur] ready; prior reads drained
    if (t + 1 < NT) LOAD((t + 1) * BK);    // issue next tile; hides under MFMA+drain
    if (active) {
      const char* pa = lds + cur * 16384;
      const char* pb = lds + 32768 + cur * 4096;
      const uint32_t kb = (uint32_t)(fq * 16);
      bf16x8 af[4], bfv[4];
#pragma unroll
      for (int mf = 0; mf < 4; ++mf)
        af[mf] = *(const bf16x8*)(pa + lrow((uint32_t)(wm + mf * 16 + fr), kb));
#pragma unroll
      for (int nf = 0; nf < 4; ++nf)
        bfv[nf] = *(const bf16x8*)(pb + lrow((uint32_t)(nf * 16 + fr), kb));
#pragma unroll
      for (int mf = 0; mf < 4; ++mf)
#pragma unroll
        for (int nf = 0; nf < 4; ++nf)
          acc[mf][nf] = __builtin_amdgcn_mfma_f32_16x16x32_bf16(af[mf], bfv[nf], acc[mf][nf], 0, 0, 0);
    }
    if (t + 1 < NT) WRITE(cur ^ 1);
    cur ^= 1;
  }

  // epilogue: silu(gate)*up -> bf16 A_ws ; gate frags nf=0,1 pair with up frags nf=2,3
  if (active) {
#pragma unroll
    for (int mf = 0; mf < 4; ++mf) {
#pragma unroll
      for (int r = 0; r < 4; ++r) {
        int grow = mt * BM + wm + mf * 16 + fq * 4 + r;
        if (grow < cnt) {
          size_t srow = (size_t)(off + grow);
#pragma unroll
          for (int nf = 0; nf < 2; ++nf) {
            float g = acc[mf][nf][r];
            float u = acc[mf][nf + 2][r];
            float val = g / (1.f + __expf(-g)) * u;
            A_ws[srow * HALFI + ns * 32 + nf * 16 + fr] = bf16b(val);
          }
        }
      }
    }
  }
}

// ---------------- GEMM2: out = (A * W2^T) * w, scatter-add ----------------
// BM=256, BN=64, BK=32, 256 threads, LDS 40KB dbuf, 3 blocks/CU.
__global__ __launch_bounds__(256, 3) void moe_gemm2(
    const uint16_t* __restrict__ A_ws, const float* __restrict__ w2,
    const int* __restrict__ offs, const int* __restrict__ tok_of_row,
    const float* __restrict__ w_of_row, float* __restrict__ out)
{
  const int s = blockIdx.x;            // 2048 = 256*8
  const int xcd = s & 7, kk = s >> 3;  // kk: 0..255
  const int mt = kk & 1, pl = kk >> 1; // pl: 0..127
  const int pair = pl * 8 + xcd;       // 0..1023
  const int e = pair >> 5, ns = pair & 31;

  const int off = offs[e];
  const int cnt = min(offs[e + 1] - off, CAP);
  if (mt * BM >= cnt) return;

  __shared__ __align__(16) char lds[40960];
  const int tid = threadIdx.x;

  // A staging (bf16 passthrough): rows j*64 + (tid>>2) (j<4), 8 bf16 at chunk (tid&3)
  const int arw = tid >> 2, c16 = tid & 3;
  int aoff[4];
  uint32_t wa[4];
#pragma unroll
  for (int j = 0; j < 4; ++j) {
    int row = j * 64 + arw;
    int grow = mt * BM + row;
    aoff[j] = (grow < cnt) ? ((off + grow) * HALFI + c16 * 8) : -1;
    wa[j] = lrow((uint32_t)row, (uint32_t)c16 * 16);
  }
  // B staging (fp32->bf16): rows = out cols ns*64 + j*32 + (tid>>3) (j<2)
  const int brw = tid >> 3, ch = tid & 7;
  const float* bp[2];
  uint32_t wb[2];
#pragma unroll
  for (int j = 0; j < 2; ++j) {
    int row = j * 32 + brw;
    bp[j] = w2 + ((size_t)e * HIDDEN + ns * 64 + row) * HALFI + ch * 4;
    wb[j] = lrow((uint32_t)row, (uint32_t)ch * 8);
  }

  uint4 raw[4]; f32x4 rb[2];

  const int lane = tid & 63, wv = tid >> 6;
  const int wm = wv * 64;
  const int fr = lane & 15, fq = lane >> 4;
  const bool active = (mt * BM + wm) < cnt;

  f32x4 acc[4][4];
#pragma unroll
  for (int i = 0; i < 4; ++i)
#pragma unroll
    for (int j = 0; j < 4; ++j) acc[i][j] = (f32x4)0.f;

  auto LOAD = [&](int k0) {
#pragma unroll
    for (int j = 0; j < 4; ++j)
      raw[j] = (aoff[j] >= 0) ? *(const uint4*)(A_ws + aoff[j] + k0) : make_uint4(0, 0, 0, 0);
#pragma unroll
    for (int j = 0; j < 2; ++j)
      rb[j] = *(const f32x4*)(bp[j] + k0);
  };
  auto WRITE = [&](int buf) {
    char* pa = lds + buf * 16384;
    char* pb = lds + 32768 + buf * 4096;
#pragma unroll
    for (int j = 0; j < 4; ++j) *(uint4*)(pa + wa[j]) = raw[j];
#pragma unroll
    for (int j = 0; j < 2; ++j) {
      uint2 v; v.x = pk2(rb[j].x, rb[j].y); v.y = pk2(rb[j].z, rb[j].w);
      *(uint2*)(pb + wb[j]) = v;
    }
  };

  const int NT = HALFI / BK;  // 44
  LOAD(0); WRITE(0);
  int cur = 0;
  for (int t = 0; t < NT; ++t) {
    __syncthreads();
    if (t + 1 < NT) LOAD((t + 1) * BK);
    if (active) {
      const char* pa = lds + cur * 16384;
      const char* pb = lds + 32768 + cur * 4096;
      const uint32_t kb = (uint32_t)(fq * 16);
      bf16x8 af[4], bfv[4];
#pragma unroll
      for (int mf = 0; mf < 4; ++mf)
        af[mf] = *(const bf16x8*)(pa + lrow((uint32_t)(wm + mf * 16 + fr), kb));
#pragma unroll
      for (int nf = 0; nf < 4; ++nf)
        bfv[nf] = *(const bf16x8*)(pb + lrow((uint32_t)(nf * 16 + fr), kb));
#pragma unroll
      for (int mf = 0; mf < 4; ++mf)
#pragma unroll
        for (int nf = 0; nf < 4; ++nf)
          acc[mf][nf] = __builtin_amdgcn_mfma_f32_16x16x32_bf16(af[mf], bfv[nf], acc[mf][nf], 0, 0, 0);
    }
    if (t + 1 < NT) WRITE(cur ^ 1);
    cur ^= 1;
  }

  // epilogue: weighted scatter-add to token rows
  if (active) {
#pragma unroll
    for (int mf = 0; mf < 4; ++mf) {
#pragma unroll
      for (int r = 0; r < 4; ++r) {
        int grow = mt * BM + wm + mf * 16 + fq * 4 + r;
        if (grow < cnt) {
          int srow = off + grow;
          int tokn = tok_of_row[srow];
          float wgt = w_of_row[srow];
          float* po = out + (size_t)tokn * HIDDEN + ns * 64 + fr;
#pragma unroll
          for (int nf = 0; nf < 4; ++nf)
            atomicAdd(po + nf * 16, acc[mf][nf][r] * wgt);
        }
      }
    }
  }
}

extern "C" void kernel_launch(void* const* d_in, const int* in_sizes, int n_in,
                              void* d_out, int out_size, void* d_ws, size_t ws_size,
                              hipStream_t stream) {
  const float* hidden = (const float*)d_in[0];
  const float* topk_w = (const float*)d_in[1];
  const float* w1     = (const float*)d_in[2];
  const float* w2     = (const float*)d_in[3];
  const int*   tkidx  = (const int*)d_in[4];

  char* ws = (char*)d_ws;
  int*      offs       = (int*)ws;                       // 33 ints
  int*      tok_of_row = (int*)(ws + 1024);              // TA ints
  float*    w_of_row   = (float*)(ws + 1024 + 4 * TA);   // TA floats
  uint16_t* A_ws       = (uint16_t*)(ws + 131072);       // TA x 1408 bf16 (~23 MB)
  float*    out        = (float*)d_out;

  hipMemsetAsync(d_out, 0, (size_t)out_size * sizeof(float), stream);
  route_count<<<1, 256, 0, stream>>>(tkidx, offs);
  route_build<<<NUM_EXPERTS, 64, 0, stream>>>(tkidx, topk_w, offs, tok_of_row, w_of_row);
  moe_gemm1<<<dim3(44 * 32 * 2), 256, 0, stream>>>(hidden, w1, offs, tok_of_row, A_ws);
  moe_gemm2<<<dim3(32 * 32 * 2), 256, 0, stream>>>(A_ws, w2, offs, tok_of_row, w_of_row, out);
}

// Round 4
// 580.644 us; speedup vs baseline: 1.2504x; 1.2504x over previous
//
#include <hip/hip_runtime.h>
#include <hip/hip_bf16.h>
#include <stdint.h>

#define NUM_EXPERTS 32
#define HIDDEN 2048
#define INTER 2816
#define HALFI 1408
#define TOKENS 1024
#define TOPK 8
#define TA (TOKENS*TOPK)
#define CAP 512
#define BM 256
#define BK 64

typedef float f32x4 __attribute__((ext_vector_type(4)));
typedef __bf16 bf16x8 __attribute__((ext_vector_type(8)));

__device__ __forceinline__ uint32_t swz(uint32_t row, uint32_t colbyte) {
  // 128-byte LDS rows (64 bf16); XOR row bits into 16B-slot bits -> conflict-free ds_read_b128
  return row * 128u + (colbyte ^ ((row & 7u) << 4));
}
__device__ __forceinline__ uint32_t pk2(float a, float b) {
  union { __bf16 h[2]; uint32_t u; } c;
  c.h[0] = (__bf16)a; c.h[1] = (__bf16)b; return c.u;
}
__device__ __forceinline__ uint16_t bf16b(float a) {
  union { __bf16 h; uint16_t u; } c; c.h = (__bf16)a; return c.u;
}

// ---------------- routing ----------------
__global__ void route_count(const int* __restrict__ tkidx, int* __restrict__ offs) {
  __shared__ int cnt[NUM_EXPERTS];
  int tid = threadIdx.x;
  if (tid < NUM_EXPERTS) cnt[tid] = 0;
  __syncthreads();
  for (int i = tid; i < TA; i += 256) atomicAdd(&cnt[tkidx[i]], 1);
  __syncthreads();
  if (tid == 0) {
    int acc = 0;
    for (int e = 0; e < NUM_EXPERTS; ++e) { offs[e] = acc; acc += cnt[e]; }
    offs[NUM_EXPERTS] = acc;
  }
}

__global__ void route_build(const int* __restrict__ tkidx, const float* __restrict__ tkw,
                            const int* __restrict__ offs,
                            int* __restrict__ tok_of_row, float* __restrict__ w_of_row) {
  int e = blockIdx.x;
  int lane = threadIdx.x;
  int base = offs[e];
  int run = 0;
  for (int c0 = 0; c0 < TA; c0 += 64) {
    int i = c0 + lane;
    bool p = (tkidx[i] == e);
    unsigned long long m = __ballot(p);
    if (p) {
      int rank = run + __popcll(m & ((1ull << lane) - 1ull));
      if (rank < CAP) {
        tok_of_row[base + rank] = i >> 3;   // TOPK = 8
        w_of_row[base + rank]   = tkw[i];
      }
    }
    run += __popcll(m);
  }
}

// ---------------- pre-pass: permuted A panel in bf16 ----------------
// A1_perm[srow][k] = bf16(hidden[tok_of_row[srow]][k]); coalesced read+write.
__global__ __launch_bounds__(256) void perm_cast(
    const float* __restrict__ hidden, const int* __restrict__ tok_of_row,
    uint16_t* __restrict__ A1_perm) {
  const int srow = blockIdx.x;
  const int tok = tok_of_row[srow] & (TOKENS - 1);   // clamp (capping never hit in practice)
  const float* src = hidden + (size_t)tok * HIDDEN + threadIdx.x * 8;
  f32x4 a = *(const f32x4*)(src);
  f32x4 b = *(const f32x4*)(src + 4);
  uint4 v;
  v.x = pk2(a.x, a.y); v.y = pk2(a.z, a.w);
  v.z = pk2(b.x, b.y); v.w = pk2(b.z, b.w);
  *(uint4*)(A1_perm + (size_t)srow * HIDDEN + threadIdx.x * 8) = v;
}

// ---------------- GEMM1: h = A1 * W1^T, a = silu(gate)*up -> A_ws (bf16) ----------------
// BM=256, BN=256 (128 gate + 128 up interleaved per wave), BK=64, 512 threads (2M x 4N waves).
// A from bf16 A1_perm (contiguous), B fp32 w1 -> cvt in staging. LDS 128KB dbuf.
__global__ __launch_bounds__(512, 2) void moe_gemm1(
    const uint16_t* __restrict__ A1_perm, const float* __restrict__ w1,
    const int* __restrict__ offs, uint16_t* __restrict__ A_ws)
{
  const int s = blockIdx.x;            // 704 = 88*8
  const int xcd = s & 7, kk = s >> 3;  // kk: 0..87
  const int mt = kk & 1, pl = kk >> 1; // pl: 0..43
  const int pair = pl * 8 + xcd;       // 0..351
  const int e = pair / 11, ns = pair % 11;

  const int off = offs[e];
  const int cnt = min(offs[e + 1] - off, CAP);
  if (mt * BM >= cnt) return;

  __shared__ __align__(16) char lds[131072];  // A dbuf 2x32KB @0, B dbuf 2x32KB @65536
  const int tid = threadIdx.x;

  // A staging: rows j*64 + (tid>>3) (j<4), 16B (8 bf16) at chunk (tid&7)
  size_t aoff[4];
  uint32_t wa[4];
#pragma unroll
  for (int j = 0; j < 4; ++j) {
    int row = j * 64 + (tid >> 3);
    int srow = min(off + mt * BM + row, TA - 1);   // rows >= cnt feed dead accumulators only
    aoff[j] = (size_t)srow * HIDDEN + (tid & 7) * 8;
    wa[j] = swz((uint32_t)row, (uint32_t)(tid & 7) * 16);
  }
  // B staging: LDS row r (j*32 + tid>>4, j<8): wn=r>>6, q=(r>>5)&1, i=r&31
  //   global col = q*HALFI + ns*128 + wn*32 + i
  const float* bp[8];
  uint32_t wb[8];
#pragma unroll
  for (int j = 0; j < 8; ++j) {
    int r = j * 32 + (tid >> 4);
    int wn = r >> 6, q = (r >> 5) & 1, i = r & 31;
    int col = q * HALFI + ns * 128 + wn * 32 + i;
    bp[j] = w1 + ((size_t)e * INTER + col) * HIDDEN + (tid & 15) * 4;
    wb[j] = swz((uint32_t)r, (uint32_t)(tid & 15) * 8);
  }

  uint4 ra[4]; f32x4 rb[8];

  const int lane = tid & 63, wv = tid >> 6;
  const int wm = (wv >> 2) * 128;        // M half
  const int wnr = (wv & 3) * 64;         // B LDS row base
  const int fr = lane & 15, fq = lane >> 4;
  const bool active = (mt * BM + wm) < cnt;

  f32x4 acc[8][4];
#pragma unroll
  for (int i = 0; i < 8; ++i)
#pragma unroll
    for (int j = 0; j < 4; ++j) acc[i][j] = (f32x4)0.f;

  auto LOAD = [&](int k0) {
#pragma unroll
    for (int j = 0; j < 4; ++j) ra[j] = *(const uint4*)(A1_perm + aoff[j] + k0);
#pragma unroll
    for (int j = 0; j < 8; ++j) rb[j] = *(const f32x4*)(bp[j] + k0);
  };
  auto WRITE = [&](int buf) {
    char* pa = lds + buf * 32768;
    char* pb = lds + 65536 + buf * 32768;
#pragma unroll
    for (int j = 0; j < 4; ++j) *(uint4*)(pa + wa[j]) = ra[j];
#pragma unroll
    for (int j = 0; j < 8; ++j) {
      uint2 v; v.x = pk2(rb[j].x, rb[j].y); v.y = pk2(rb[j].z, rb[j].w);
      *(uint2*)(pb + wb[j]) = v;
    }
  };

  const int NT = HIDDEN / BK;  // 32
  LOAD(0); WRITE(0);
  int cur = 0;
  for (int t = 0; t < NT; ++t) {
    __syncthreads();
    if (t + 1 < NT) LOAD((t + 1) * BK);
    if (active) {
      const char* pa = lds + cur * 32768;
      const char* pb = lds + 65536 + cur * 32768;
#pragma unroll
      for (int ks = 0; ks < 2; ++ks) {
        const uint32_t kb = (uint32_t)(ks * 64 + fq * 16);
        bf16x8 af[8], bfv[4];
#pragma unroll
        for (int mf = 0; mf < 8; ++mf)
          af[mf] = *(const bf16x8*)(pa + swz((uint32_t)(wm + mf * 16 + fr), kb));
#pragma unroll
        for (int nf = 0; nf < 4; ++nf)
          bfv[nf] = *(const bf16x8*)(pb + swz((uint32_t)(wnr + nf * 16 + fr), kb));
#pragma unroll
        for (int mf = 0; mf < 8; ++mf)
#pragma unroll
          for (int nf = 0; nf < 4; ++nf)
            acc[mf][nf] = __builtin_amdgcn_mfma_f32_16x16x32_bf16(af[mf], bfv[nf], acc[mf][nf], 0, 0, 0);
      }
    }
    if (t + 1 < NT) WRITE(cur ^ 1);
    cur ^= 1;
  }

  // epilogue: gate frags nf 0,1 pair with up frags nf 2,3 (same i range)
  if (active) {
#pragma unroll
    for (int mf = 0; mf < 8; ++mf) {
#pragma unroll
      for (int r = 0; r < 4; ++r) {
        int grow = mt * BM + wm + mf * 16 + fq * 4 + r;
        if (grow < cnt) {
          size_t srow = (size_t)(off + grow);
#pragma unroll
          for (int nf = 0; nf < 2; ++nf) {
            float g = acc[mf][nf][r];
            float u = acc[mf][nf + 2][r];
            float val = g / (1.f + __expf(-g)) * u;
            A_ws[srow * HALFI + ns * 128 + (wv & 3) * 32 + nf * 16 + fr] = bf16b(val);
          }
        }
      }
    }
  }
}

// ---------------- GEMM2: out = (A_ws * W2^T) * w, scatter-add ----------------
// BM=256, BN=256, BK=64, 512 threads (2M x 4N waves). A bf16 contiguous, B fp32 w2.
__global__ __launch_bounds__(512, 2) void moe_gemm2(
    const uint16_t* __restrict__ A_ws, const float* __restrict__ w2,
    const int* __restrict__ offs, const int* __restrict__ tok_of_row,
    const float* __restrict__ w_of_row, float* __restrict__ out)
{
  const int s = blockIdx.x;            // 512 = 64*8
  const int xcd = s & 7, kk = s >> 3;  // kk: 0..63
  const int mt = kk & 1, pl = kk >> 1; // pl: 0..31
  const int pair = pl * 8 + xcd;       // 0..255
  const int e = pair >> 3, ns = pair & 7;

  const int off = offs[e];
  const int cnt = min(offs[e + 1] - off, CAP);
  if (mt * BM >= cnt) return;

  __shared__ __align__(16) char lds[131072];
  const int tid = threadIdx.x;

  // A staging: rows j*64 + (tid>>3) (j<4), 16B at chunk (tid&7)
  size_t aoff[4];
  uint32_t wa[4];
#pragma unroll
  for (int j = 0; j < 4; ++j) {
    int row = j * 64 + (tid >> 3);
    int srow = min(off + mt * BM + row, TA - 1);
    aoff[j] = (size_t)srow * HALFI + (tid & 7) * 8;
    wa[j] = swz((uint32_t)row, (uint32_t)(tid & 7) * 16);
  }
  // B staging: LDS row r = out col ns*256 + r
  const float* bp[8];
  uint32_t wb[8];
#pragma unroll
  for (int j = 0; j < 8; ++j) {
    int r = j * 32 + (tid >> 4);
    bp[j] = w2 + ((size_t)e * HIDDEN + ns * 256 + r) * HALFI + (tid & 15) * 4;
    wb[j] = swz((uint32_t)r, (uint32_t)(tid & 15) * 8);
  }

  uint4 ra[4]; f32x4 rb[8];

  const int lane = tid & 63, wv = tid >> 6;
  const int wm = (wv >> 2) * 128;
  const int wnr = (wv & 3) * 64;
  const int fr = lane & 15, fq = lane >> 4;
  const bool active = (mt * BM + wm) < cnt;

  f32x4 acc[8][4];
#pragma unroll
  for (int i = 0; i < 8; ++i)
#pragma unroll
    for (int j = 0; j < 4; ++j) acc[i][j] = (f32x4)0.f;

  auto LOAD = [&](int k0) {
#pragma unroll
    for (int j = 0; j < 4; ++j) ra[j] = *(const uint4*)(A_ws + aoff[j] + k0);
#pragma unroll
    for (int j = 0; j < 8; ++j) rb[j] = *(const f32x4*)(bp[j] + k0);
  };
  auto WRITE = [&](int buf) {
    char* pa = lds + buf * 32768;
    char* pb = lds + 65536 + buf * 32768;
#pragma unroll
    for (int j = 0; j < 4; ++j) *(uint4*)(pa + wa[j]) = ra[j];
#pragma unroll
    for (int j = 0; j < 8; ++j) {
      uint2 v; v.x = pk2(rb[j].x, rb[j].y); v.y = pk2(rb[j].z, rb[j].w);
      *(uint2*)(pb + wb[j]) = v;
    }
  };

  const int NT = HALFI / BK;  // 22
  LOAD(0); WRITE(0);
  int cur = 0;
  for (int t = 0; t < NT; ++t) {
    __syncthreads();
    if (t + 1 < NT) LOAD((t + 1) * BK);
    if (active) {
      const char* pa = lds + cur * 32768;
      const char* pb = lds + 65536 + cur * 32768;
#pragma unroll
      for (int ks = 0; ks < 2; ++ks) {
        const uint32_t kb = (uint32_t)(ks * 64 + fq * 16);
        bf16x8 af[8], bfv[4];
#pragma unroll
        for (int mf = 0; mf < 8; ++mf)
          af[mf] = *(const bf16x8*)(pa + swz((uint32_t)(wm + mf * 16 + fr), kb));
#pragma unroll
        for (int nf = 0; nf < 4; ++nf)
          bfv[nf] = *(const bf16x8*)(pb + swz((uint32_t)(wnr + nf * 16 + fr), kb));
#pragma unroll
        for (int mf = 0; mf < 8; ++mf)
#pragma unroll
          for (int nf = 0; nf < 4; ++nf)
            acc[mf][nf] = __builtin_amdgcn_mfma_f32_16x16x32_bf16(af[mf], bfv[nf], acc[mf][nf], 0, 0, 0);
      }
    }
    if (t + 1 < NT) WRITE(cur ^ 1);
    cur ^= 1;
  }

  if (active) {
#pragma unroll
    for (int mf = 0; mf < 8; ++mf) {
#pragma unroll
      for (int r = 0; r < 4; ++r) {
        int grow = mt * BM + wm + mf * 16 + fq * 4 + r;
        if (grow < cnt) {
          int srow = off + grow;
          int tokn = tok_of_row[srow];
          float wgt = w_of_row[srow];
          float* po = out + (size_t)tokn * HIDDEN + ns * 256 + (wv & 3) * 64 + fr;
#pragma unroll
          for (int nf = 0; nf < 4; ++nf)
            atomicAdd(po + nf * 16, acc[mf][nf][r] * wgt);
        }
      }
    }
  }
}

extern "C" void kernel_launch(void* const* d_in, const int* in_sizes, int n_in,
                              void* d_out, int out_size, void* d_ws, size_t ws_size,
                              hipStream_t stream) {
  const float* hidden = (const float*)d_in[0];
  const float* topk_w = (const float*)d_in[1];
  const float* w1     = (const float*)d_in[2];
  const float* w2     = (const float*)d_in[3];
  const int*   tkidx  = (const int*)d_in[4];

  char* ws = (char*)d_ws;
  int*      offs       = (int*)ws;                         // 33 ints
  int*      tok_of_row = (int*)(ws + 1024);                // TA ints
  float*    w_of_row   = (float*)(ws + 1024 + 4 * TA);     // TA floats
  uint16_t* A1_perm    = (uint16_t*)(ws + 131072);         // TA x 2048 bf16 (33.5 MB)
  uint16_t* A_ws       = (uint16_t*)(ws + 131072 + (size_t)TA * HIDDEN * 2);  // TA x 1408 bf16 (23 MB)
  float*    out        = (float*)d_out;

  hipMemsetAsync(d_out, 0, (size_t)out_size * sizeof(float), stream);
  route_count<<<1, 256, 0, stream>>>(tkidx, offs);
  route_build<<<NUM_EXPERTS, 64, 0, stream>>>(tkidx, topk_w, offs, tok_of_row, w_of_row);
  perm_cast<<<TA, 256, 0, stream>>>(hidden, tok_of_row, A1_perm);
  moe_gemm1<<<dim3(44 * 2 * 8), 512, 0, stream>>>(A1_perm, w1, offs, A_ws);
  moe_gemm2<<<dim3(32 * 2 * 8), 512, 0, stream>>>(A_ws, w2, offs, tok_of_row, w_of_row, out);
}